// Round 2
// baseline (1459.804 us; speedup 1.0000x reference)
//
#include <hip/hip_runtime.h>
#include <math.h>

#define N_   8
#define C_   64
#define H_   128
#define W_   128
#define HW_  (H_ * W_)
#define CHW_ (C_ * HW_)
#define K_   3
#define CI_TILE 16
#define TILE 16
#define HALO (TILE + 2)          // 18
#define LDS_STRIDE 20            // rows 16B-aligned (20*4=80B), enables ds_read_b128
#define BN_EPS 1e-5
#define POW_EPS 1e-12f

// Kernel 1: y = adder2d(x, W) + x.
// Block: 256 threads = 64 pixel-threads x 4 co-groups.
//   pixel-thread: row r (16), w-segment s (4) -> 4 consecutive pixels.
//   co-group g (wave-uniform, threadIdx>>6): 8 output channels.
// Grid: (64 spatial tiles, N, 2 co-halves) = 1024 blocks -> 4 blocks/CU.
// Each thread: acc[4 pixels][8 co] = 32 VGPR accumulators.
__global__ __launch_bounds__(256, 4) void adder_kernel(
    const float* __restrict__ x, const float* __restrict__ weight,
    float* __restrict__ y)
{
    __shared__ float sx[CI_TILE][HALO][LDS_STRIDE];

    const int lane = threadIdx.x & 63;
    const int cog  = threadIdx.x >> 6;    // 0..3, wave-uniform
    const int s    = lane & 3;            // w segment (4 pixels each)
    const int r    = lane >> 2;           // row 0..15
    const int tile = blockIdx.x;          // 64 spatial tiles
    const int n    = blockIdx.y;
    const int co_base = blockIdx.z * 32 + cog * 8;
    const int h0 = (tile >> 3) * TILE;
    const int w0 = (tile & 7) * TILE;

    float acc[4][8];
#pragma unroll
    for (int p = 0; p < 4; ++p)
#pragma unroll
        for (int co = 0; co < 8; ++co) acc[p][co] = 0.f;

    const float* xn = x + n * CHW_;

    for (int cb = 0; cb < C_; cb += CI_TILE) {
        __syncthreads();
        // Stage CI_TILE x 18 x 18 halo tile, zero-filled outside image.
        for (int idx = threadIdx.x; idx < CI_TILE * HALO * HALO; idx += 256) {
            int ci  = idx / (HALO * HALO);
            int rem = idx - ci * (HALO * HALO);
            int rr  = rem / HALO;
            int cc  = rem - rr * HALO;
            int gh  = h0 + rr - 1;
            int gw  = w0 + cc - 1;
            float v = 0.f;
            if ((unsigned)gh < (unsigned)H_ && (unsigned)gw < (unsigned)W_)
                v = xn[(cb + ci) * HW_ + gh * W_ + gw];
            sx[ci][rr][cc] = v;
        }
        __syncthreads();

#pragma unroll 1
        for (int ci = 0; ci < CI_TILE; ++ci) {
            // x window: rows r..r+2, cols 4s..4s+5 (6 used; load 8 as f4+f2, aligned)
            float xr[3][8];
#pragma unroll
            for (int kh = 0; kh < 3; ++kh) {
                const float* row = &sx[ci][r + kh][4 * s];
                float4 a = *reinterpret_cast<const float4*>(row);       // ds_read_b128
                float2 b = *reinterpret_cast<const float2*>(row + 4);   // ds_read_b64
                xr[kh][0] = a.x; xr[kh][1] = a.y; xr[kh][2] = a.z; xr[kh][3] = a.w;
                xr[kh][4] = b.x; xr[kh][5] = b.y;
            }

            // Wave-uniform weight pointer -> scalar (s_load) fetches.
            const float* wp = weight + co_base * (C_ * 9) + (cb + ci) * 9;
#pragma unroll
            for (int co = 0; co < 8; ++co) {
                const float* wc = wp + co * (C_ * 9);
                float wv[9];
#pragma unroll
                for (int k = 0; k < 9; ++k) wv[k] = wc[k];
#pragma unroll
                for (int p = 0; p < 4; ++p) {
                    float t = fabsf(xr[0][p]     - wv[0]) + fabsf(xr[0][p + 1] - wv[1])
                            + fabsf(xr[0][p + 2] - wv[2]) + fabsf(xr[1][p]     - wv[3])
                            + fabsf(xr[1][p + 1] - wv[4]) + fabsf(xr[1][p + 2] - wv[5])
                            + fabsf(xr[2][p]     - wv[6]) + fabsf(xr[2][p + 1] - wv[7])
                            + fabsf(xr[2][p + 2] - wv[8]);
                    acc[p][co] += t;
                }
            }
        }
    }

    // Store y = -acc + residual x, one float4 per co (16B aligned: w0+4s).
    const int pix = (h0 + r) * W_ + w0 + 4 * s;
#pragma unroll
    for (int co = 0; co < 8; ++co) {
        const float* xr4 = xn + (co_base + co) * HW_ + pix;
        float4 res = *reinterpret_cast<const float4*>(xr4);
        float4 o;
        o.x = -acc[0][co] + res.x;
        o.y = -acc[1][co] + res.y;
        o.z = -acc[2][co] + res.z;
        o.w = -acc[3][co] + res.w;
        *reinterpret_cast<float4*>(y + n * CHW_ + (co_base + co) * HW_ + pix) = o;
    }
}

// Kernel 2: per-channel sum / sumsq over (N,H,W); double atomics into d_ws.
__global__ __launch_bounds__(256) void stats_kernel(
    const float* __restrict__ y, double* __restrict__ sums)
{
    const int c = blockIdx.x;
    const int n = blockIdx.y;
    const float* p = y + n * CHW_ + c * HW_;

    float s = 0.f, ss = 0.f;
    for (int i = threadIdx.x; i < HW_; i += 256) {
        float v = p[i];
        s += v;
        ss += v * v;
    }
#pragma unroll
    for (int off = 32; off > 0; off >>= 1) {
        s  += __shfl_down(s, off);
        ss += __shfl_down(ss, off);
    }
    __shared__ float rs[4], rss[4];
    const int lane = threadIdx.x & 63;
    const int wid  = threadIdx.x >> 6;
    if (lane == 0) { rs[wid] = s; rss[wid] = ss; }
    __syncthreads();
    if (threadIdx.x == 0) {
        float S  = rs[0] + rs[1] + rs[2] + rs[3];
        float SS = rss[0] + rss[1] + rss[2] + rss[3];
        atomicAdd(&sums[c], (double)S);
        atomicAdd(&sums[C_ + c], (double)SS);
    }
}

// Kernel 3: per-channel scale/shift from batch stats.
__global__ void finalize_kernel(const double* __restrict__ sums,
                                const float* __restrict__ gamma,
                                const float* __restrict__ beta,
                                float* __restrict__ sc)
{
    const int c = threadIdx.x;  // 64 threads
    const double cnt = (double)(N_ * HW_);
    double mean = sums[c] / cnt;
    double var  = sums[C_ + c] / cnt - mean * mean;
    float inv   = (float)(1.0 / sqrt(var + (double)BN_EPS));
    float scale = gamma[c] * inv;
    float shift = beta[c] - (float)mean * scale;
    sc[c]      = scale;
    sc[C_ + c] = shift;
}

// Kernel 4: in-place BN affine + power activation, float4 vectorized.
__global__ __launch_bounds__(256) void apply_kernel(
    float* __restrict__ y, const float* __restrict__ sc,
    const float* __restrict__ alpha_p)
{
    const int idx = blockIdx.x * 256 + threadIdx.x;   // float4 index
    const float alpha = alpha_p[0];
    const int e0 = idx * 4;
    const int c = (e0 / HW_) & (C_ - 1);
    const float scale = sc[c];
    const float shift = sc[C_ + c];

    float4 v = reinterpret_cast<float4*>(y)[idx];
    float* pv = reinterpret_cast<float*>(&v);
#pragma unroll
    for (int i = 0; i < 4; ++i) {
        float t = pv[i] * scale + shift;
        float sgn = (t > 0.f) ? 1.f : ((t < 0.f) ? -1.f : 0.f);
        pv[i] = sgn * powf(fabsf(t) + POW_EPS, alpha);
    }
    reinterpret_cast<float4*>(y)[idx] = v;
}

extern "C" void kernel_launch(void* const* d_in, const int* in_sizes, int n_in,
                              void* d_out, int out_size, void* d_ws, size_t ws_size,
                              hipStream_t stream)
{
    const float* x      = (const float*)d_in[0];
    const float* weight = (const float*)d_in[1];
    const float* gamma  = (const float*)d_in[2];
    const float* beta   = (const float*)d_in[3];
    const float* alpha  = (const float*)d_in[4];
    float* out = (float*)d_out;

    double* sums = (double*)d_ws;                                // 128 doubles
    float*  sc   = (float*)((char*)d_ws + 128 * sizeof(double)); // 128 floats

    hipMemsetAsync(d_ws, 0, 128 * sizeof(double), stream);

    adder_kernel<<<dim3(64, N_, 2), 256, 0, stream>>>(x, weight, out);
    stats_kernel<<<dim3(C_, N_), 256, 0, stream>>>(out, sums);
    finalize_kernel<<<1, C_, 0, stream>>>(sums, gamma, beta, sc);

    const int n4 = (N_ * CHW_) / 4;
    apply_kernel<<<n4 / 256, 256, 0, stream>>>(out, sc, alpha);
}

// Round 3
// 864.207 us; speedup vs baseline: 1.6892x; 1.6892x over previous
//
#include <hip/hip_runtime.h>
#include <math.h>

#define N_   8
#define C_   64
#define H_   128
#define W_   128
#define HW_  (H_ * W_)
#define CHW_ (C_ * HW_)
#define K_   3
#define CI_TILE 16
#define TILE 16
#define HALO (TILE + 2)          // 18
#define LDS_STRIDE 20            // 80B rows: 16B-aligned, conflict-free with r-fast lane map
#define BN_EPS 1e-5
#define POW_EPS 1e-12f

// Kernel 1: y = adder2d(x, W) + x.
// Block: 256 threads = 64 pixel-threads x 4 co-groups (wave-uniform co group).
//   lane: r = lane&15 (row), s = lane>>4 (4-pixel w segment)  [r-fast => LDS
//   b128 reads at stride 20 hit all 32 banks once per 8-lane phase]
//   cog = readfirstlane(threadIdx>>6): FORCES SGPR weight addressing (s_load,
//   weights in SGPRs, no VGPR pressure -> no scratch spill; round-2 lesson).
// Grid: (64 tiles, N, 2 co-halves) = 1024 blocks -> 4 blocks/CU, 16 waves/CU.
// Each thread: acc[4 px][8 co] = 32 VGPR accumulators.
__global__ __launch_bounds__(256, 4) void adder_kernel(
    const float* __restrict__ x, const float* __restrict__ weight,
    float* __restrict__ y)
{
    __shared__ __align__(16) float sx[CI_TILE][HALO][LDS_STRIDE];

    const int lane = threadIdx.x & 63;
    const int cog  = __builtin_amdgcn_readfirstlane(threadIdx.x >> 6); // SGPR
    const int r    = lane & 15;           // row 0..15 (fast)
    const int s    = lane >> 4;           // w segment 0..3
    const int tile = blockIdx.x;          // 64 spatial tiles
    const int n    = blockIdx.y;
    const int co_base = blockIdx.z * 32 + cog * 8;   // fully scalar
    const int h0 = (tile >> 3) * TILE;
    const int w0 = (tile & 7) * TILE;

    float acc[4][8];
#pragma unroll
    for (int p = 0; p < 4; ++p)
#pragma unroll
        for (int co = 0; co < 8; ++co) acc[p][co] = 0.f;

    const float* xn = x + n * CHW_;

    for (int cb = 0; cb < C_; cb += CI_TILE) {
        __syncthreads();
        // Stage CI_TILE x 18 x 18 halo tile, zero-filled outside image
        // (zero padding contributes |0 - w| at borders).
        for (int idx = threadIdx.x; idx < CI_TILE * HALO * HALO; idx += 256) {
            int ci  = idx / (HALO * HALO);
            int rem = idx - ci * (HALO * HALO);
            int rr  = rem / HALO;
            int cc  = rem - rr * HALO;
            int gh  = h0 + rr - 1;
            int gw  = w0 + cc - 1;
            float v = 0.f;
            if ((unsigned)gh < (unsigned)H_ && (unsigned)gw < (unsigned)W_)
                v = xn[(cb + ci) * HW_ + gh * W_ + gw];
            sx[ci][rr][cc] = v;
        }
        __syncthreads();

#pragma unroll 1
        for (int ci = 0; ci < CI_TILE; ++ci) {
            // x window: rows r..r+2, cols 4s..4s+5 (load 8: aligned f4 + f2)
            float xr[3][8];
#pragma unroll
            for (int kh = 0; kh < 3; ++kh) {
                const float* row = &sx[ci][r + kh][4 * s];
                float4 a = *reinterpret_cast<const float4*>(row);       // ds_read_b128
                float2 b = *reinterpret_cast<const float2*>(row + 4);   // ds_read_b64
                xr[kh][0] = a.x; xr[kh][1] = a.y; xr[kh][2] = a.z; xr[kh][3] = a.w;
                xr[kh][4] = b.x; xr[kh][5] = b.y;
            }

            // Scalar weight pointer -> s_load into SGPRs (no VGPR cost).
            const float* wp = weight + co_base * (C_ * 9) + (cb + ci) * 9;
#pragma unroll
            for (int co = 0; co < 8; ++co) {
                const float* wc = wp + co * (C_ * 9);
                float wv[9];
#pragma unroll
                for (int k = 0; k < 9; ++k) wv[k] = wc[k];
#pragma unroll
                for (int p = 0; p < 4; ++p) {
                    float t = fabsf(xr[0][p]     - wv[0]) + fabsf(xr[0][p + 1] - wv[1])
                            + fabsf(xr[0][p + 2] - wv[2]) + fabsf(xr[1][p]     - wv[3])
                            + fabsf(xr[1][p + 1] - wv[4]) + fabsf(xr[1][p + 2] - wv[5])
                            + fabsf(xr[2][p]     - wv[6]) + fabsf(xr[2][p + 1] - wv[7])
                            + fabsf(xr[2][p + 2] - wv[8]);
                    acc[p][co] += t;
                }
            }
        }
    }

    // Store y = -acc + residual x, one float4 per co (16B aligned: w0+4s).
    const int pix = (h0 + r) * W_ + w0 + 4 * s;
#pragma unroll
    for (int co = 0; co < 8; ++co) {
        const float* xr4 = xn + (co_base + co) * HW_ + pix;
        float4 res = *reinterpret_cast<const float4*>(xr4);
        float4 o;
        o.x = -acc[0][co] + res.x;
        o.y = -acc[1][co] + res.y;
        o.z = -acc[2][co] + res.z;
        o.w = -acc[3][co] + res.w;
        *reinterpret_cast<float4*>(y + n * CHW_ + (co_base + co) * HW_ + pix) = o;
    }
}

// Kernel 2: per-channel sum / sumsq over (N,H,W); double atomics into d_ws.
__global__ __launch_bounds__(256) void stats_kernel(
    const float* __restrict__ y, double* __restrict__ sums)
{
    const int c = blockIdx.x;
    const int n = blockIdx.y;
    const float* p = y + n * CHW_ + c * HW_;

    float s = 0.f, ss = 0.f;
    for (int i = threadIdx.x; i < HW_; i += 256) {
        float v = p[i];
        s += v;
        ss += v * v;
    }
#pragma unroll
    for (int off = 32; off > 0; off >>= 1) {
        s  += __shfl_down(s, off);
        ss += __shfl_down(ss, off);
    }
    __shared__ float rs[4], rss[4];
    const int lane = threadIdx.x & 63;
    const int wid  = threadIdx.x >> 6;
    if (lane == 0) { rs[wid] = s; rss[wid] = ss; }
    __syncthreads();
    if (threadIdx.x == 0) {
        float S  = rs[0] + rs[1] + rs[2] + rs[3];
        float SS = rss[0] + rss[1] + rss[2] + rss[3];
        atomicAdd(&sums[c], (double)S);
        atomicAdd(&sums[C_ + c], (double)SS);
    }
}

// Kernel 3: per-channel scale/shift from batch stats.
__global__ void finalize_kernel(const double* __restrict__ sums,
                                const float* __restrict__ gamma,
                                const float* __restrict__ beta,
                                float* __restrict__ sc)
{
    const int c = threadIdx.x;  // 64 threads
    const double cnt = (double)(N_ * HW_);
    double mean = sums[c] / cnt;
    double var  = sums[C_ + c] / cnt - mean * mean;
    float inv   = (float)(1.0 / sqrt(var + (double)BN_EPS));
    float scale = gamma[c] * inv;
    float shift = beta[c] - (float)mean * scale;
    sc[c]      = scale;
    sc[C_ + c] = shift;
}

// Kernel 4: in-place BN affine + power activation, float4 vectorized.
__global__ __launch_bounds__(256) void apply_kernel(
    float* __restrict__ y, const float* __restrict__ sc,
    const float* __restrict__ alpha_p)
{
    const int idx = blockIdx.x * 256 + threadIdx.x;   // float4 index
    const float alpha = alpha_p[0];
    const int e0 = idx * 4;
    const int c = (e0 / HW_) & (C_ - 1);
    const float scale = sc[c];
    const float shift = sc[C_ + c];

    float4 v = reinterpret_cast<float4*>(y)[idx];
    float* pv = reinterpret_cast<float*>(&v);
#pragma unroll
    for (int i = 0; i < 4; ++i) {
        float t = pv[i] * scale + shift;
        float sgn = (t > 0.f) ? 1.f : ((t < 0.f) ? -1.f : 0.f);
        pv[i] = sgn * powf(fabsf(t) + POW_EPS, alpha);
    }
    reinterpret_cast<float4*>(y)[idx] = v;
}

extern "C" void kernel_launch(void* const* d_in, const int* in_sizes, int n_in,
                              void* d_out, int out_size, void* d_ws, size_t ws_size,
                              hipStream_t stream)
{
    const float* x      = (const float*)d_in[0];
    const float* weight = (const float*)d_in[1];
    const float* gamma  = (const float*)d_in[2];
    const float* beta   = (const float*)d_in[3];
    const float* alpha  = (const float*)d_in[4];
    float* out = (float*)d_out;

    double* sums = (double*)d_ws;                                // 128 doubles
    float*  sc   = (float*)((char*)d_ws + 128 * sizeof(double)); // 128 floats

    hipMemsetAsync(d_ws, 0, 128 * sizeof(double), stream);

    adder_kernel<<<dim3(64, N_, 2), 256, 0, stream>>>(x, weight, out);
    stats_kernel<<<dim3(C_, N_), 256, 0, stream>>>(out, sums);
    finalize_kernel<<<1, C_, 0, stream>>>(sums, gamma, beta, sc);

    const int n4 = (N_ * CHW_) / 4;
    apply_kernel<<<n4 / 256, 256, 0, stream>>>(out, sc, alpha);
}

// Round 4
// 681.303 us; speedup vs baseline: 2.1427x; 1.2685x over previous
//
#include <hip/hip_runtime.h>
#include <math.h>

#define N_   8
#define C_   64
#define H_   128
#define W_   128
#define HW_  (H_ * W_)
#define CHW_ (C_ * HW_)
#define K_   3
#define CI_TILE 16
#define TILE 16
#define HALO (TILE + 2)          // 18
#define LDS_STRIDE 20            // 80B x-rows: 16B-aligned, conflict-free b128 reads
#define WROW 12                  // weight row pad 9->12 floats: 48B, 16B-aligned
#define BN_EPS 1e-5
#define POW_EPS 1e-12f

// Kernel 1: y = adder2d(x, W) + x.
// Round-4 structure: weights staged in LDS per ci-chunk (round 2/3 lesson:
// keeping 72 weights in registers per ci iteration forces acc[] to spill ->
// 2.5 GB scratch traffic). LDS weight reads are wave-broadcast (all lanes
// same addr) and loaded right before use -> ~12 transient VGPRs.
// Block: 256 threads = 64 pixel-threads x 4 co-groups (8 co each).
//   lane: r = lane&15 (row), s = lane>>4 (4-px w segment).
// Grid: (64 tiles, N, 2 co-halves) = 1024 blocks. LDS 47.6KB -> 3 blocks/CU.
// Per thread: acc[4 px][8 co] = 32 VGPR accumulators.
__global__ __launch_bounds__(256, 3) void adder_kernel(
    const float* __restrict__ x, const float* __restrict__ weight,
    float* __restrict__ y)
{
    __shared__ __align__(16) float sx[CI_TILE][HALO][LDS_STRIDE];
    __shared__ __align__(16) float sw[32 * CI_TILE * WROW];  // [co][ci][12]

    const int lane = threadIdx.x & 63;
    const int cog  = threadIdx.x >> 6;    // 0..3 (wave-uniform by construction)
    const int r    = lane & 15;           // row 0..15 (fast -> conflict-free b128)
    const int s    = lane >> 4;           // w segment 0..3
    const int tile = blockIdx.x;          // 64 spatial tiles
    const int n    = blockIdx.y;
    const int co0  = blockIdx.z * 32;     // block's co base (scalar)
    const int h0 = (tile >> 3) * TILE;
    const int w0 = (tile & 7) * TILE;

    float acc[4][8];
#pragma unroll
    for (int p = 0; p < 4; ++p)
#pragma unroll
        for (int co = 0; co < 8; ++co) acc[p][co] = 0.f;

    const float* xn = x + n * CHW_;

    for (int cb = 0; cb < C_; cb += CI_TILE) {
        __syncthreads();  // protect previous chunk's reads before overwrite

        // Stage x: CI_TILE x 18 x 18 halo, zero-filled outside image
        // (zero padding contributes |0 - w| at borders).
        for (int idx = threadIdx.x; idx < CI_TILE * HALO * HALO; idx += 256) {
            int ci  = idx / (HALO * HALO);
            int rem = idx - ci * (HALO * HALO);
            int rr  = rem / HALO;
            int cc  = rem - rr * HALO;
            int gh  = h0 + rr - 1;
            int gw  = w0 + cc - 1;
            float v = 0.f;
            if ((unsigned)gh < (unsigned)H_ && (unsigned)gw < (unsigned)W_)
                v = xn[(cb + ci) * HW_ + gh * W_ + gw];
            sx[ci][rr][cc] = v;
        }

        // Stage weights: 32 co x CI_TILE ci x 9 -> padded rows of 12.
        // 4608 elements = 18 per thread, coalesced global reads.
#pragma unroll
        for (int t = 0; t < 18; ++t) {
            int idx = threadIdx.x + t * 256;           // 0..4607
            int co  = idx / (CI_TILE * 9);
            int rem = idx - co * (CI_TILE * 9);
            int ci  = rem / 9;
            int k   = rem - ci * 9;
            sw[(co * CI_TILE + ci) * WROW + k] =
                weight[(co0 + co) * (C_ * 9) + (cb + ci) * 9 + k];
        }
        __syncthreads();

#pragma unroll 1
        for (int ci = 0; ci < CI_TILE; ++ci) {
            // x window: rows r..r+2, cols 4s..4s+5 (aligned f4 + f2 loads)
            float xr[3][8];
#pragma unroll
            for (int kh = 0; kh < 3; ++kh) {
                const float* row = &sx[ci][r + kh][4 * s];
                float4 a = *reinterpret_cast<const float4*>(row);       // ds_read_b128
                float2 b = *reinterpret_cast<const float2*>(row + 4);   // ds_read_b64
                xr[kh][0] = a.x; xr[kh][1] = a.y; xr[kh][2] = a.z; xr[kh][3] = a.w;
                xr[kh][4] = b.x; xr[kh][5] = b.y;
            }

#pragma unroll
            for (int co = 0; co < 8; ++co) {
                // Broadcast LDS reads (all lanes same addr): b128 + b128 + b32
                const float* wc = &sw[((cog * 8 + co) * CI_TILE + ci) * WROW];
                float4 wa = *reinterpret_cast<const float4*>(wc);
                float4 wb = *reinterpret_cast<const float4*>(wc + 4);
                float  w8 = wc[8];
#pragma unroll
                for (int p = 0; p < 4; ++p) {
                    float t = fabsf(xr[0][p]     - wa.x) + fabsf(xr[0][p + 1] - wa.y)
                            + fabsf(xr[0][p + 2] - wa.z) + fabsf(xr[1][p]     - wa.w)
                            + fabsf(xr[1][p + 1] - wb.x) + fabsf(xr[1][p + 2] - wb.y)
                            + fabsf(xr[2][p]     - wb.z) + fabsf(xr[2][p + 1] - wb.w)
                            + fabsf(xr[2][p + 2] - w8);
                    acc[p][co] += t;
                }
            }
        }
    }

    // Store y = -acc + residual x, one float4 per co (16B aligned: w0+4s).
    const int pix = (h0 + r) * W_ + w0 + 4 * s;
#pragma unroll
    for (int co = 0; co < 8; ++co) {
        const int coc = co0 + cog * 8 + co;
        float4 res = *reinterpret_cast<const float4*>(xn + coc * HW_ + pix);
        float4 o;
        o.x = -acc[0][co] + res.x;
        o.y = -acc[1][co] + res.y;
        o.z = -acc[2][co] + res.z;
        o.w = -acc[3][co] + res.w;
        *reinterpret_cast<float4*>(y + n * CHW_ + coc * HW_ + pix) = o;
    }
}

// Kernel 2: per-channel sum / sumsq over (N,H,W); double atomics into d_ws.
__global__ __launch_bounds__(256) void stats_kernel(
    const float* __restrict__ y, double* __restrict__ sums)
{
    const int c = blockIdx.x;
    const int n = blockIdx.y;
    const float* p = y + n * CHW_ + c * HW_;

    float s = 0.f, ss = 0.f;
    for (int i = threadIdx.x; i < HW_; i += 256) {
        float v = p[i];
        s += v;
        ss += v * v;
    }
#pragma unroll
    for (int off = 32; off > 0; off >>= 1) {
        s  += __shfl_down(s, off);
        ss += __shfl_down(ss, off);
    }
    __shared__ float rs[4], rss[4];
    const int lane = threadIdx.x & 63;
    const int wid  = threadIdx.x >> 6;
    if (lane == 0) { rs[wid] = s; rss[wid] = ss; }
    __syncthreads();
    if (threadIdx.x == 0) {
        float S  = rs[0] + rs[1] + rs[2] + rs[3];
        float SS = rss[0] + rss[1] + rss[2] + rss[3];
        atomicAdd(&sums[c], (double)S);
        atomicAdd(&sums[C_ + c], (double)SS);
    }
}

// Kernel 3: per-channel scale/shift from batch stats.
__global__ void finalize_kernel(const double* __restrict__ sums,
                                const float* __restrict__ gamma,
                                const float* __restrict__ beta,
                                float* __restrict__ sc)
{
    const int c = threadIdx.x;  // 64 threads
    const double cnt = (double)(N_ * HW_);
    double mean = sums[c] / cnt;
    double var  = sums[C_ + c] / cnt - mean * mean;
    float inv   = (float)(1.0 / sqrt(var + (double)BN_EPS));
    float scale = gamma[c] * inv;
    float shift = beta[c] - (float)mean * scale;
    sc[c]      = scale;
    sc[C_ + c] = shift;
}

// Kernel 4: in-place BN affine + power activation, float4 vectorized.
__global__ __launch_bounds__(256) void apply_kernel(
    float* __restrict__ y, const float* __restrict__ sc,
    const float* __restrict__ alpha_p)
{
    const int idx = blockIdx.x * 256 + threadIdx.x;   // float4 index
    const float alpha = alpha_p[0];
    const int e0 = idx * 4;
    const int c = (e0 / HW_) & (C_ - 1);
    const float scale = sc[c];
    const float shift = sc[C_ + c];

    float4 v = reinterpret_cast<float4*>(y)[idx];
    float* pv = reinterpret_cast<float*>(&v);
#pragma unroll
    for (int i = 0; i < 4; ++i) {
        float t = pv[i] * scale + shift;
        float sgn = (t > 0.f) ? 1.f : ((t < 0.f) ? -1.f : 0.f);
        pv[i] = sgn * powf(fabsf(t) + POW_EPS, alpha);
    }
    reinterpret_cast<float4*>(y)[idx] = v;
}

extern "C" void kernel_launch(void* const* d_in, const int* in_sizes, int n_in,
                              void* d_out, int out_size, void* d_ws, size_t ws_size,
                              hipStream_t stream)
{
    const float* x      = (const float*)d_in[0];
    const float* weight = (const float*)d_in[1];
    const float* gamma  = (const float*)d_in[2];
    const float* beta   = (const float*)d_in[3];
    const float* alpha  = (const float*)d_in[4];
    float* out = (float*)d_out;

    double* sums = (double*)d_ws;                                // 128 doubles
    float*  sc   = (float*)((char*)d_ws + 128 * sizeof(double)); // 128 floats

    hipMemsetAsync(d_ws, 0, 128 * sizeof(double), stream);

    adder_kernel<<<dim3(64, N_, 2), 256, 0, stream>>>(x, weight, out);
    stats_kernel<<<dim3(C_, N_), 256, 0, stream>>>(out, sums);
    finalize_kernel<<<1, C_, 0, stream>>>(sums, gamma, beta, sc);

    const int n4 = (N_ * CHW_) / 4;
    apply_kernel<<<n4 / 256, 256, 0, stream>>>(out, sc, alpha);
}